// Round 6
// baseline (1145.242 us; speedup 1.0000x reference)
//
#include <hip/hip_runtime.h>

// MV_GCN on MI355X — round 6: column-quarter split for 2 blocks/CU.
// Each block = (g, v, q): computes 32 of the 128 GCN channels for one view.
//   phase 1: H_q = X @ W[:,q]   (X in sA, W_q fully LDS-resident -> 0 barriers)
//   phase 2: A_hat built in sA from edges (per-block rebuild; L3 absorbs reuse)
//   phase 3: out_q = A_hat @ H_q, 16-lane max, cross-block max via monotone-
//            encoded atomicMax (max of identical values -> bit-exact).
// All fma chains bit-identical to R5 (which scored absmax 0.0): ascending k/s,
// same deg/normalize/rsqrtf sequences. NO reassociation (R4 lesson).
// LDS: sA 55.7K + sWH 15.8K + dinv 0.5K = 72 KB -> 2 blocks/CU = 8 waves/SIMD.
// __launch_bounds__(1024,8): VGPR cap 64; per-thread state ~40 regs (acc[2]x2,
// edge batch 21) — fits. Spill tripwire: VGPR_Count<40 + WRITE_SIZE huge.

#define NB 256
#define NODES 116
#define FEAT 115
#define LENN 6670
#define SEG2 13456
#define HID 128
#define HC 512
#define ASTR 120   // sA row stride (480 B; rows land on distinct bank phases)
#define QC 32      // channels per quarter
#define HSTR 34    // H row stride in sWH (136 B)

__device__ __forceinline__ unsigned enc_f32(float f) {
  unsigned b = __float_as_uint(f);
  return (b & 0x80000000u) ? ~b : (b | 0x80000000u);   // monotone order-preserving
}
__device__ __forceinline__ float dec_f32(unsigned u) {
  unsigned b = (u & 0x80000000u) ? (u ^ 0x80000000u) : ~u;
  return __uint_as_float(b);
}

__global__ __launch_bounds__(1024, 8) void k_fused_q(
    const float* __restrict__ x, const int* __restrict__ ei,
    const float* __restrict__ ew,
    const float* __restrict__ W1, const float* __restrict__ b1,
    const float* __restrict__ W2, const float* __restrict__ b2,
    unsigned* __restrict__ featenc)
{
  __shared__ __align__(16) float sA[NODES * ASTR];  // X (ph1), A_hat (ph2/3)
  __shared__ __align__(16) float sWH[NODES * HSTR]; // W_q rows (ph1), H_q (ph3)
  __shared__ float dinv[NODES];

  const int bid = blockIdx.x;
  const int g = bid >> 3, v = (bid >> 2) & 1, q = bid & 3;
  const int tid = threadIdx.x;
  const float* __restrict__ W  = (v ? W2 : W1) + q * QC;
  const float* __restrict__ bv = (v ? b2 : b1) + q * QC;
  const float* __restrict__ xg = x + (size_t)(g * 232 + v * 116) * FEAT;

  // ---- stage X into sA (pad cols [115,120) = 0) ----
  for (int i = tid; i < NODES * ASTR; i += 1024) {
    int r = i / ASTR;
    int k = i - r * ASTR;
    sA[i] = (k < FEAT) ? xg[r * FEAT + k] : 0.f;
  }
  // ---- stage W_q fully: 120 rows x 32 cols (rows >=115 zero) ----
  for (int j = 0; j < 4; ++j) {
    int idx = tid + j * 1024;
    if (idx < 120 * QC) {
      int wrow = idx >> 5, wcol = idx & 31;
      sWH[idx] = (wrow < FEAT) ? W[(size_t)wrow * HID + wcol] : 0.f;
    }
  }
  __syncthreads();

  // thread tile: cg = tid&15 -> 2 cols (32 cols), rg = tid>>4 -> rows rg, rg+64
  const int cg = tid & 15, rg = tid >> 4;
  const int c0 = cg * 2;
  int rr[2];
  rr[0] = rg;                                   // 0..63, always valid
  rr[1] = (rg + 64 < NODES) ? rg + 64 : NODES - 1;  // clamp dup (identical values)

  // ================= phase 1: H_q = X @ W_q (no barriers in loop) ==========
  float2 acc[2];
  acc[0] = make_float2(0.f, 0.f);
  acc[1] = make_float2(0.f, 0.f);

  for (int ch = 0; ch < 15; ++ch) {            // k = 0..119, pads exact +0.0
    const int k0 = 8 * ch;
    float2 wv[8];
#pragma unroll
    for (int j = 0; j < 8; ++j) wv[j] = *(const float2*)&sWH[(k0 + j) * QC + c0];
#pragma unroll
    for (int i = 0; i < 2; ++i) {
      const float* ap = &sA[rr[i] * ASTR + k0];
      float4 a0 = *(const float4*)ap;          // 4-addr bcast, conflict-free
      float4 a1 = *(const float4*)(ap + 4);
      acc[i].x = fmaf(a0.x, wv[0].x, acc[i].x);
      acc[i].y = fmaf(a0.x, wv[0].y, acc[i].y);
      acc[i].x = fmaf(a0.y, wv[1].x, acc[i].x);
      acc[i].y = fmaf(a0.y, wv[1].y, acc[i].y);
      acc[i].x = fmaf(a0.z, wv[2].x, acc[i].x);
      acc[i].y = fmaf(a0.z, wv[2].y, acc[i].y);
      acc[i].x = fmaf(a0.w, wv[3].x, acc[i].x);
      acc[i].y = fmaf(a0.w, wv[3].y, acc[i].y);
      acc[i].x = fmaf(a1.x, wv[4].x, acc[i].x);
      acc[i].y = fmaf(a1.x, wv[4].y, acc[i].y);
      acc[i].x = fmaf(a1.y, wv[5].x, acc[i].x);
      acc[i].y = fmaf(a1.y, wv[5].y, acc[i].y);
      acc[i].x = fmaf(a1.z, wv[6].x, acc[i].x);
      acc[i].y = fmaf(a1.z, wv[6].y, acc[i].y);
      acc[i].x = fmaf(a1.w, wv[7].x, acc[i].x);
      acc[i].y = fmaf(a1.w, wv[7].y, acc[i].y);
    }
  }
  __syncthreads();                             // all W_q + X reads done

  // H_q -> sWH (stride HSTR, overwrites dead W_q); clamp-dups identical
#pragma unroll
  for (int i = 0; i < 2; ++i)
    *(float2*)&sWH[rr[i] * HSTR + c0] = acc[i];
  __syncthreads();

  // ================= build A_hat in sA =================
  const float4 z4 = make_float4(0.f, 0.f, 0.f, 0.f);
  for (int i = tid; i < (NODES * ASTR) / 4; i += 1024) ((float4*)sA)[i] = z4;
  __syncthreads();

  {  // edge pass: A_raw[d][s] += w (pipelined predicated loads)
    const int eoff = g * SEG2 + v * LENN;
    const int nbase = g * 232 + v * 116;
    const int* __restrict__ srcp = ei + eoff;
    const int* __restrict__ dstp = ei + (size_t)NB * SEG2 + eoff;
    const float* __restrict__ wp = ew + eoff;
    int ss[7], dd[7];
    float ww[7];
#pragma unroll
    for (int j = 0; j < 7; ++j) {
      const int e = tid + j * 1024;
      const bool ok = (e < LENN);
      ss[j] = ok ? (srcp[e] - nbase) : 0;
      dd[j] = ok ? (dstp[e] - nbase) : 0;
      ww[j] = ok ? wp[e] : 0.f;
    }
#pragma unroll
    for (int j = 0; j < 7; ++j)
      atomicAdd(&sA[dd[j] * ASTR + ss[j]], ww[j]);
  }
  __syncthreads();

  // deg -> dinv (4 threads/row, stride-29; sequence identical to R5)
  if (tid < 4 * NODES) {
    const int r = tid >> 2, qq = tid & 3;
    const float* row = &sA[r * ASTR + qq * 29];
    float s = 0.f;
#pragma unroll
    for (int j = 0; j < 29; ++j) s += row[j];
    s += __shfl_xor(s, 1, 64);
    s += __shfl_xor(s, 2, 64);
    if (qq == 0) dinv[r] = rsqrtf(s + 1.0f);   // deg + 1 self-loop
  }
  __syncthreads();

  // normalize in place; self-loop dinv^2 on diagonal (identical expression)
  for (int idx = tid; idx < NODES * NODES; idx += 1024) {
    int d = idx / NODES;
    int s = idx - d * NODES;
    float di = dinv[d];
    float val = sA[d * ASTR + s] * (di * dinv[s]);
    if (d == s) val += di * di;
    sA[d * ASTR + s] = val;
  }
  __syncthreads();

  // ================= phase 3: out_q = A_hat @ H_q + b (all LDS) ============
  float2 acc2[2];
  {
    float2 bb = *(const float2*)(bv + c0);
    acc2[0] = bb;
    acc2[1] = bb;
  }

  for (int sc = 0; sc < 29; ++sc) {            // s = 0..115, ascending (R5 order)
    const int s0 = 4 * sc;
    float2 hv[4];
#pragma unroll
    for (int j = 0; j < 4; ++j) hv[j] = *(const float2*)&sWH[(s0 + j) * HSTR + c0];
#pragma unroll
    for (int i = 0; i < 2; ++i) {
      float4 a = *(const float4*)&sA[rr[i] * ASTR + s0];
      acc2[i].x = fmaf(a.x, hv[0].x, acc2[i].x);
      acc2[i].y = fmaf(a.x, hv[0].y, acc2[i].y);
      acc2[i].x = fmaf(a.y, hv[1].x, acc2[i].x);
      acc2[i].y = fmaf(a.y, hv[1].y, acc2[i].y);
      acc2[i].x = fmaf(a.z, hv[2].x, acc2[i].x);
      acc2[i].y = fmaf(a.z, hv[2].y, acc2[i].y);
      acc2[i].x = fmaf(a.w, hv[3].x, acc2[i].x);
      acc2[i].y = fmaf(a.w, hv[3].y, acc2[i].y);
    }
  }

  // ---- max over this block's 32 channels (16 lanes), then cross-block ----
#pragma unroll
  for (int i = 0; i < 2; ++i) {
    float m = fmaxf(acc2[i].x, acc2[i].y);
    m = fmaxf(m, __shfl_xor(m, 1, 64));
    m = fmaxf(m, __shfl_xor(m, 2, 64));
    m = fmaxf(m, __shfl_xor(m, 4, 64));
    m = fmaxf(m, __shfl_xor(m, 8, 64));        // max over the 16-lane col group
    if (cg == 0)
      atomicMax(&featenc[g * 232 + 2 * rr[i] + v], enc_f32(m));
  }
}

// ---------------- K3: MLP  relu(feat@W6+b6)@W7+b7 ----------------
__global__ __launch_bounds__(512) void k_mlp(
    const unsigned* __restrict__ featenc, const float* __restrict__ W6,
    const float* __restrict__ b6, const float* __restrict__ W7,
    const float* __restrict__ b7, float* __restrict__ out)
{
  __shared__ float sf[232];
  __shared__ float red[8];
  const int g = blockIdx.x, tid = threadIdx.x;
  if (tid < 232) sf[tid] = dec_f32(featenc[g * 232 + tid]);
  __syncthreads();

  float a = b6[tid];
  const float* __restrict__ w6p = W6 + tid;
#pragma unroll 8
  for (int k = 0; k < 232; ++k)
    a = fmaf(sf[k], w6p[(size_t)k * HC], a);
  a = fmaxf(a, 0.f);
  float p = a * W7[tid];
#pragma unroll
  for (int off = 32; off >= 1; off >>= 1) p += __shfl_xor(p, off, 64);
  if ((tid & 63) == 0) red[tid >> 6] = p;
  __syncthreads();
  if (tid == 0) {
    float t = b7[0];
#pragma unroll
    for (int i = 0; i < 8; ++i) t += red[i];
    out[g] = t;
  }
}

extern "C" void kernel_launch(void* const* d_in, const int* in_sizes, int n_in,
                              void* d_out, int out_size, void* d_ws, size_t ws_size,
                              hipStream_t stream)
{
  const float* x  = (const float*)d_in[0];
  const int*   ei = (const int*)d_in[1];
  const float* ew = (const float*)d_in[2];
  // d_in[3] = batch (unused by reference)
  const float* W1 = (const float*)d_in[4];
  const float* b1 = (const float*)d_in[5];
  const float* W2 = (const float*)d_in[6];
  const float* b2 = (const float*)d_in[7];
  const float* W6 = (const float*)d_in[8];
  const float* b6 = (const float*)d_in[9];
  const float* W7 = (const float*)d_in[10];
  const float* b7 = (const float*)d_in[11];

  unsigned* featenc = (unsigned*)d_ws;     // 256*232 u32 (encoded running max)
  float* out = (float*)d_out;

  // ws is re-poisoned 0xAA before every launch; atomicMax needs 0-init
  // (enc 0 < enc of every float). hipMemsetAsync is graph-capture safe.
  hipMemsetAsync(featenc, 0, (size_t)NB * 232 * sizeof(unsigned), stream);

  hipLaunchKernelGGL(k_fused_q, dim3(8 * NB), dim3(1024), 0, stream,
                     x, ei, ew, W1, b1, W2, b2, featenc);
  hipLaunchKernelGGL(k_mlp, dim3(NB), dim3(512), 0, stream,
                     featenc, W6, b6, W7, b7, out);
}

// Round 7
// 976.342 us; speedup vs baseline: 1.1730x; 1.1730x over previous
//
#include <hip/hip_runtime.h>

// MV_GCN on MI355X — round 7: R6 structure, spill fixed.
// R6 post-mortem: __launch_bounds__(1024,8) (VGPR cap 64) made the allocator
// spill catastrophically (VGPR_Count=32, 2.46 GB scratch writes) — second
// occurrence after R3. Occupancy here is LDS-limited (72 KB -> 2 blocks/CU),
// so (1024,4) keeps the same 8 waves/SIMD potential iff natural VGPR <= 64,
// without ever forcing a spill.
// Structure (validated bit-exact in R6, absmax 0.0):
// block = (g, v, q): 32 of 128 channels.
//   phase 1: H_q = X @ W[:,q]  (X in sA, W_q fully LDS-resident, 0 barriers)
//   phase 2: A_hat built in sA from edges (per-block rebuild, L3 absorbs 4x)
//   phase 3: out_q = A_hat @ H_q, 16-lane max, cross-block monotone atomicMax.

#define NB 256
#define NODES 116
#define FEAT 115
#define LENN 6670
#define SEG2 13456
#define HID 128
#define HC 512
#define ASTR 120   // sA row stride (480 B)
#define QC 32      // channels per quarter
#define HSTR 34    // H row stride in sWH (136 B)

__device__ __forceinline__ unsigned enc_f32(float f) {
  unsigned b = __float_as_uint(f);
  return (b & 0x80000000u) ? ~b : (b | 0x80000000u);   // monotone order-preserving
}
__device__ __forceinline__ float dec_f32(unsigned u) {
  unsigned b = (u & 0x80000000u) ? (u ^ 0x80000000u) : ~u;
  return __uint_as_float(b);
}

__global__ __launch_bounds__(1024, 4) void k_fused_q(
    const float* __restrict__ x, const int* __restrict__ ei,
    const float* __restrict__ ew,
    const float* __restrict__ W1, const float* __restrict__ b1,
    const float* __restrict__ W2, const float* __restrict__ b2,
    unsigned* __restrict__ featenc)
{
  __shared__ __align__(16) float sA[NODES * ASTR];  // X (ph1), A_hat (ph2/3)
  __shared__ __align__(16) float sWH[NODES * HSTR]; // W_q rows (ph1), H_q (ph3)
  __shared__ float dinv[NODES];

  const int bid = blockIdx.x;
  const int g = bid >> 3, v = (bid >> 2) & 1, q = bid & 3;
  const int tid = threadIdx.x;
  const float* __restrict__ W  = (v ? W2 : W1) + q * QC;
  const float* __restrict__ bv = (v ? b2 : b1) + q * QC;
  const float* __restrict__ xg = x + (size_t)(g * 232 + v * 116) * FEAT;

  // ---- stage X into sA (pad cols [115,120) = 0) ----
  for (int i = tid; i < NODES * ASTR; i += 1024) {
    int r = i / ASTR;
    int k = i - r * ASTR;
    sA[i] = (k < FEAT) ? xg[r * FEAT + k] : 0.f;
  }
  // ---- stage W_q fully: 120 rows x 32 cols (rows >=115 zero) ----
  for (int j = 0; j < 4; ++j) {
    int idx = tid + j * 1024;
    if (idx < 120 * QC) {
      int wrow = idx >> 5, wcol = idx & 31;
      sWH[idx] = (wrow < FEAT) ? W[(size_t)wrow * HID + wcol] : 0.f;
    }
  }
  __syncthreads();

  // thread tile: cg = tid&15 -> 2 cols (32 cols), rg = tid>>4 -> rows rg, rg+64
  const int cg = tid & 15, rg = tid >> 4;
  const int c0 = cg * 2;
  int rr[2];
  rr[0] = rg;                                   // 0..63, always valid
  rr[1] = (rg + 64 < NODES) ? rg + 64 : NODES - 1;  // clamp dup (identical values)

  // ================= phase 1: H_q = X @ W_q (no barriers in loop) ==========
  float2 acc[2];
  acc[0] = make_float2(0.f, 0.f);
  acc[1] = make_float2(0.f, 0.f);

  for (int ch = 0; ch < 15; ++ch) {            // k = 0..119, pads exact +0.0
    const int k0 = 8 * ch;
    float2 wv[8];
#pragma unroll
    for (int j = 0; j < 8; ++j) wv[j] = *(const float2*)&sWH[(k0 + j) * QC + c0];
#pragma unroll
    for (int i = 0; i < 2; ++i) {
      const float* ap = &sA[rr[i] * ASTR + k0];
      float4 a0 = *(const float4*)ap;          // 4-addr multicast, conflict-free
      float4 a1 = *(const float4*)(ap + 4);
      acc[i].x = fmaf(a0.x, wv[0].x, acc[i].x);
      acc[i].y = fmaf(a0.x, wv[0].y, acc[i].y);
      acc[i].x = fmaf(a0.y, wv[1].x, acc[i].x);
      acc[i].y = fmaf(a0.y, wv[1].y, acc[i].y);
      acc[i].x = fmaf(a0.z, wv[2].x, acc[i].x);
      acc[i].y = fmaf(a0.z, wv[2].y, acc[i].y);
      acc[i].x = fmaf(a0.w, wv[3].x, acc[i].x);
      acc[i].y = fmaf(a0.w, wv[3].y, acc[i].y);
      acc[i].x = fmaf(a1.x, wv[4].x, acc[i].x);
      acc[i].y = fmaf(a1.x, wv[4].y, acc[i].y);
      acc[i].x = fmaf(a1.y, wv[5].x, acc[i].x);
      acc[i].y = fmaf(a1.y, wv[5].y, acc[i].y);
      acc[i].x = fmaf(a1.z, wv[6].x, acc[i].x);
      acc[i].y = fmaf(a1.z, wv[6].y, acc[i].y);
      acc[i].x = fmaf(a1.w, wv[7].x, acc[i].x);
      acc[i].y = fmaf(a1.w, wv[7].y, acc[i].y);
    }
  }
  __syncthreads();                             // all W_q + X reads done

  // H_q -> sWH (stride HSTR, overwrites dead W_q); clamp-dups identical
#pragma unroll
  for (int i = 0; i < 2; ++i)
    *(float2*)&sWH[rr[i] * HSTR + c0] = acc[i];
  __syncthreads();

  // ================= build A_hat in sA =================
  const float4 z4 = make_float4(0.f, 0.f, 0.f, 0.f);
  for (int i = tid; i < (NODES * ASTR) / 4; i += 1024) ((float4*)sA)[i] = z4;
  __syncthreads();

  {  // edge pass: A_raw[d][s] += w (pipelined predicated loads)
    const int eoff = g * SEG2 + v * LENN;
    const int nbase = g * 232 + v * 116;
    const int* __restrict__ srcp = ei + eoff;
    const int* __restrict__ dstp = ei + (size_t)NB * SEG2 + eoff;
    const float* __restrict__ wp = ew + eoff;
    int ss[7], dd[7];
    float ww[7];
#pragma unroll
    for (int j = 0; j < 7; ++j) {
      const int e = tid + j * 1024;
      const bool ok = (e < LENN);
      ss[j] = ok ? (srcp[e] - nbase) : 0;
      dd[j] = ok ? (dstp[e] - nbase) : 0;
      ww[j] = ok ? wp[e] : 0.f;
    }
#pragma unroll
    for (int j = 0; j < 7; ++j)
      atomicAdd(&sA[dd[j] * ASTR + ss[j]], ww[j]);
  }
  __syncthreads();

  // deg -> dinv (4 threads/row, stride-29; sequence identical to R5/R6)
  if (tid < 4 * NODES) {
    const int r = tid >> 2, qq = tid & 3;
    const float* row = &sA[r * ASTR + qq * 29];
    float s = 0.f;
#pragma unroll
    for (int j = 0; j < 29; ++j) s += row[j];
    s += __shfl_xor(s, 1, 64);
    s += __shfl_xor(s, 2, 64);
    if (qq == 0) dinv[r] = rsqrtf(s + 1.0f);   // deg + 1 self-loop
  }
  __syncthreads();

  // normalize in place; self-loop dinv^2 on diagonal (identical expression)
  for (int idx = tid; idx < NODES * NODES; idx += 1024) {
    int d = idx / NODES;
    int s = idx - d * NODES;
    float di = dinv[d];
    float val = sA[d * ASTR + s] * (di * dinv[s]);
    if (d == s) val += di * di;
    sA[d * ASTR + s] = val;
  }
  __syncthreads();

  // ================= phase 3: out_q = A_hat @ H_q + b (all LDS) ============
  float2 acc2[2];
  {
    float2 bb = *(const float2*)(bv + c0);
    acc2[0] = bb;
    acc2[1] = bb;
  }

  for (int sc = 0; sc < 29; ++sc) {            // s = 0..115, ascending (R5 order)
    const int s0 = 4 * sc;
    float2 hv[4];
#pragma unroll
    for (int j = 0; j < 4; ++j) hv[j] = *(const float2*)&sWH[(s0 + j) * HSTR + c0];
#pragma unroll
    for (int i = 0; i < 2; ++i) {
      float4 a = *(const float4*)&sA[rr[i] * ASTR + s0];
      acc2[i].x = fmaf(a.x, hv[0].x, acc2[i].x);
      acc2[i].y = fmaf(a.x, hv[0].y, acc2[i].y);
      acc2[i].x = fmaf(a.y, hv[1].x, acc2[i].x);
      acc2[i].y = fmaf(a.y, hv[1].y, acc2[i].y);
      acc2[i].x = fmaf(a.z, hv[2].x, acc2[i].x);
      acc2[i].y = fmaf(a.z, hv[2].y, acc2[i].y);
      acc2[i].x = fmaf(a.w, hv[3].x, acc2[i].x);
      acc2[i].y = fmaf(a.w, hv[3].y, acc2[i].y);
    }
  }

  // ---- max over this block's 32 channels (16 lanes), then cross-block ----
#pragma unroll
  for (int i = 0; i < 2; ++i) {
    float m = fmaxf(acc2[i].x, acc2[i].y);
    m = fmaxf(m, __shfl_xor(m, 1, 64));
    m = fmaxf(m, __shfl_xor(m, 2, 64));
    m = fmaxf(m, __shfl_xor(m, 4, 64));
    m = fmaxf(m, __shfl_xor(m, 8, 64));        // max over the 16-lane col group
    if (cg == 0)
      atomicMax(&featenc[g * 232 + 2 * rr[i] + v], enc_f32(m));
  }
}

// ---------------- K3: MLP  relu(feat@W6+b6)@W7+b7 ----------------
__global__ __launch_bounds__(512) void k_mlp(
    const unsigned* __restrict__ featenc, const float* __restrict__ W6,
    const float* __restrict__ b6, const float* __restrict__ W7,
    const float* __restrict__ b7, float* __restrict__ out)
{
  __shared__ float sf[232];
  __shared__ float red[8];
  const int g = blockIdx.x, tid = threadIdx.x;
  if (tid < 232) sf[tid] = dec_f32(featenc[g * 232 + tid]);
  __syncthreads();

  float a = b6[tid];
  const float* __restrict__ w6p = W6 + tid;
#pragma unroll 8
  for (int k = 0; k < 232; ++k)
    a = fmaf(sf[k], w6p[(size_t)k * HC], a);
  a = fmaxf(a, 0.f);
  float p = a * W7[tid];
#pragma unroll
  for (int off = 32; off >= 1; off >>= 1) p += __shfl_xor(p, off, 64);
  if ((tid & 63) == 0) red[tid >> 6] = p;
  __syncthreads();
  if (tid == 0) {
    float t = b7[0];
#pragma unroll
    for (int i = 0; i < 8; ++i) t += red[i];
    out[g] = t;
  }
}

extern "C" void kernel_launch(void* const* d_in, const int* in_sizes, int n_in,
                              void* d_out, int out_size, void* d_ws, size_t ws_size,
                              hipStream_t stream)
{
  const float* x  = (const float*)d_in[0];
  const int*   ei = (const int*)d_in[1];
  const float* ew = (const float*)d_in[2];
  // d_in[3] = batch (unused by reference)
  const float* W1 = (const float*)d_in[4];
  const float* b1 = (const float*)d_in[5];
  const float* W2 = (const float*)d_in[6];
  const float* b2 = (const float*)d_in[7];
  const float* W6 = (const float*)d_in[8];
  const float* b6 = (const float*)d_in[9];
  const float* W7 = (const float*)d_in[10];
  const float* b7 = (const float*)d_in[11];

  unsigned* featenc = (unsigned*)d_ws;     // 256*232 u32 (encoded running max)
  float* out = (float*)d_out;

  // ws is re-poisoned 0xAA before every launch; atomicMax needs 0-init
  // (enc 0 < enc of every float). hipMemsetAsync is graph-capture safe.
  hipMemsetAsync(featenc, 0, (size_t)NB * 232 * sizeof(unsigned), stream);

  hipLaunchKernelGGL(k_fused_q, dim3(8 * NB), dim3(1024), 0, stream,
                     x, ei, ew, W1, b1, W2, b2, featenc);
  hipLaunchKernelGGL(k_mlp, dim3(NB), dim3(512), 0, stream,
                     featenc, W6, b6, W7, b7, out);
}